// Round 6
// baseline (118.422 us; speedup 1.0000x reference)
//
#include <hip/hip_runtime.h>
#include <hip/hip_bf16.h>
#include <math.h>

#define NN 512
#define L2E 1.44269504089f
typedef __attribute__((ext_vector_type(8))) short short8;
typedef __attribute__((ext_vector_type(4))) float f32x4;
typedef __attribute__((ext_vector_type(16))) float f32x16;

// ws float offsets
#define OFF_XLI  0u         // interleaved xl: [inst][t=j>>6][q=d>>2][j&63][d&3]
#define OFF_XR   524288u
#define OFF_VV   1048576u
#define OFF_SA   1056768u
#define OFF_XLTH 1056896u   // bf16 hi, transposed [inst][d][j]
#define OFF_XLTL 1319040u   // bf16 lo
#define OFF_H1   1581184u
#define OFF_H2   2105472u

// ---------------- GEMM + v/sa + interleaved & transposed copies ----------------
template<int K>
__global__ __launch_bounds__(256) void kpre(
    const float* __restrict__ src, int srcPerInst,
    const float* __restrict__ Wl0, const float* __restrict__ Wr0, const float* __restrict__ a0,
    const float* __restrict__ Wl1, const float* __restrict__ Wr1, const float* __restrict__ a1,
    float* __restrict__ ws)
{
    __shared__ float xs[8 * K];
    const int rb   = blockIdx.x;   // 0..63 : 8-row block
    const int inst = blockIdx.y;   // 0..15 (br*8 + batch)
    const int br   = inst >> 3;
    const int tid  = threadIdx.x;
    const int d = tid & 63, ig = tid >> 6;
    const float* Wl = br ? Wl1 : Wl0;
    const float* Wr = br ? Wr1 : Wr0;
    const float* av = br ? a1  : a0;
    const float* sp = src + (size_t)(srcPerInst ? inst : (inst & 7)) * NN * K + (size_t)rb * 8 * K;

    if (tid < 2 * K) ((float4*)xs)[tid] = ((const float4*)sp)[tid];
    __syncthreads();

    float accl[2] = {0.f, 0.f}, accr[2] = {0.f, 0.f};
#pragma unroll 16
    for (int k = 0; k < K; ++k) {
        float wl = Wl[k * 64 + d];            // coalesced, L2-hot
        float wr = Wr[k * 64 + d];
#pragma unroll
        for (int rr = 0; rr < 2; ++rr) {
            float xv = xs[(ig * 2 + rr) * K + k];   // wave-uniform broadcast
            accl[rr] = fmaf(xv, wl, accl[rr]);
            accr[rr] = fmaf(xv, wr, accr[rr]);
        }
    }

    float aval = av[d];
    float* XLI = ws + OFF_XLI; float* XR = ws + OFF_XR;
    float* VV  = ws + OFF_VV;  float* SA = ws + OFF_SA;
    __hip_bfloat16* XLTH = (__hip_bfloat16*)(ws + OFF_XLTH);
    __hip_bfloat16* XLTL = (__hip_bfloat16*)(ws + OFF_XLTL);
#pragma unroll
    for (int rr = 0; rr < 2; ++rr) {
        int row = rb * 8 + ig * 2 + rr;
        XR[(size_t)(inst * NN + row) * 64 + d] = accr[rr];
        // interleaved xl for kattn's coalesced per-lane row loads
        XLI[(((size_t)inst * 8 + (row >> 6)) * 16 + (d >> 2)) * 256 + (row & 63) * 4 + (d & 3)] = accl[rr];
        // transposed bf16 hi/lo for the MFMA B-operand
        __hip_bfloat16 h  = __float2bfloat16(accl[rr]);
        __hip_bfloat16 lo = __float2bfloat16(accl[rr] - __bfloat162float(h));
        size_t ot = (size_t)(inst * 64 + d) * NN + row;
        XLTH[ot] = h; XLTL[ot] = lo;
        float pv = aval * accl[rr];
#pragma unroll
        for (int mm = 32; mm > 0; mm >>= 1) pv += __shfl_xor(pv, mm, 64);
        if (d == 0) VV[inst * NN + row] = 0.6f * L2E * pv;   // log2e folded
    }
    if (rb == 0 && ig == 0 && (inst & 7) == 0) SA[br * 64 + d] = 0.4f * L2E * aval;  // log2e folded
}

// ------- fused attention: SMEM (s_load) scoring, wave-private p, MFMA PV + den -------
__global__ __launch_bounds__(512, 4) void kattn(
    const float* __restrict__ ws,
    const float* __restrict__ b0, const float* __restrict__ b1,
    float* __restrict__ Hout)
{
    __shared__ __hip_bfloat16 pbuf[8][2048];   // per-wave p: 1024 hi + 1024 lo (32 KB)
    __shared__ float pout[8][1056];            // partial outs [w][i][66] (33 KB)

    const int ib   = blockIdx.x;        // 0..31 : 16 i-rows
    const int inst = blockIdx.y;        // 0..15
    const int br   = inst >> 3;
    const int tid  = threadIdx.x;
    const int lane = tid & 63;
    const int w    = __builtin_amdgcn_readfirstlane(tid >> 6);   // wave id 0..7
    const float* XR  = ws + OFF_XR + (size_t)inst * NN * 64;
    const float* VV  = ws + OFF_VV + inst * NN;
    const float* SAp = ws + OFF_SA + br * 64;
    const __hip_bfloat16* XLTH = (const __hip_bfloat16*)(ws + OFF_XLTH) + (size_t)inst * 64 * NN;
    const __hip_bfloat16* XLTL = (const __hip_bfloat16*)(ws + OFF_XLTL) + (size_t)inst * 64 * NN;
    const float* bias = br ? b1 : b0;

    // per-lane xl row (j = w*64+lane), coalesced from interleaved layout; loaded once
    const float4* xli4 = (const float4*)(ws + OFF_XLI) + ((size_t)inst * 8 + w) * 1024;
    float xlv[64];
#pragma unroll
    for (int q = 0; q < 16; ++q) {
        float4 v = xli4[q * 64 + lane];
        xlv[4*q+0] = v.x; xlv[4*q+1] = v.y; xlv[4*q+2] = v.z; xlv[4*q+3] = v.w;
    }
    float vj = VV[w * 64 + lane];

    __hip_bfloat16* phw = pbuf[w];          // wave-private: no barriers needed
    __hip_bfloat16* plw = pbuf[w] + 1024;

    // ---------------- scoring + p : xr/sa via guaranteed scalar loads ----------------
    const float* xr_base = XR + (size_t)(ib * 16) * 64;
    for (int ii = 0; ii < 16; ++ii) {
        const float* xr_row = xr_base + ii * 64;
        float a0 = 0.f, a1 = 0.f, a2 = 0.f, a3 = 0.f;
#pragma unroll
        for (int q = 0; q < 4; ++q) {
            f32x16 xr16, sa16;
            // self-contained: loads + drain in ONE asm block (SMEM returns are
            // out-of-order -> only lgkmcnt(0) is safe; data-dep via outputs
            // orders consumers after the wait). TLP (4 waves/SIMD) hides the stall.
            asm volatile(
                "s_load_dwordx16 %0, %2, 0\n\t"
                "s_load_dwordx16 %1, %3, 0\n\t"
                "s_waitcnt lgkmcnt(0)"
                : "=&s"(xr16), "=&s"(sa16)
                : "s"(xr_row + q * 16), "s"(SAp + q * 16)
                : "memory");
#pragma unroll
            for (int c = 0; c < 16; c += 4) {
                a0 = fmaf(sa16[c+0], fabsf(xr16[c+0] + xlv[q*16+c+0]), a0);
                a1 = fmaf(sa16[c+1], fabsf(xr16[c+1] + xlv[q*16+c+1]), a1);
                a2 = fmaf(sa16[c+2], fabsf(xr16[c+2] + xlv[q*16+c+2]), a2);
                a3 = fmaf(sa16[c+3], fabsf(xr16[c+3] + xlv[q*16+c+3]), a3);
            }
        }
        float p = exp2f(((a0 + a1) + (a2 + a3)) + vj);
        __hip_bfloat16 h  = __float2bfloat16(p);
        __hip_bfloat16 lo = __float2bfloat16(p - __bfloat162float(h));
        int idx = ii * 64 + (((lane >> 3) ^ (ii & 7)) << 3) + (lane & 7);
        phw[idx] = h; plw[idx] = lo;
    }

    // ---------------- PV + den via MFMA (wave-private A-frags) ----------------
    f32x4 accn[4] = {{0,0,0,0},{0,0,0,0},{0,0,0,0},{0,0,0,0}};
    f32x4 accd = {0, 0, 0, 0};
    const short8 ones = {16256,16256,16256,16256,16256,16256,16256,16256};  // bf16 1.0
#pragma unroll
    for (int ks = 0; ks < 2; ++ks) {
        int aidx = (lane & 15) * 64 + ((((ks << 2) + (lane >> 4)) ^ (lane & 7)) << 3);
        short8 ah = *(const short8*)&phw[aidx];
        short8 al = *(const short8*)&plw[aidx];
        int jb = w * 64 + ks * 32 + (lane >> 4) * 8;
#pragma unroll
        for (int dt = 0; dt < 4; ++dt) {
            float4 bhv = *(const float4*)&XLTH[(size_t)(dt * 16 + (lane & 15)) * NN + jb];
            float4 blv = *(const float4*)&XLTL[(size_t)(dt * 16 + (lane & 15)) * NN + jb];
            short8 bh = __builtin_bit_cast(short8, bhv);
            short8 bl = __builtin_bit_cast(short8, blv);
            accn[dt] = __builtin_amdgcn_mfma_f32_16x16x32_bf16(ah, bh, accn[dt], 0, 0, 0);
            accn[dt] = __builtin_amdgcn_mfma_f32_16x16x32_bf16(al, bh, accn[dt], 0, 0, 0);
            accn[dt] = __builtin_amdgcn_mfma_f32_16x16x32_bf16(ah, bl, accn[dt], 0, 0, 0);
        }
        accd = __builtin_amdgcn_mfma_f32_16x16x32_bf16(ah, ones, accd, 0, 0, 0);
        accd = __builtin_amdgcn_mfma_f32_16x16x32_bf16(al, ones, accd, 0, 0, 0);
    }

    // partial outs -> LDS: pout[w][i][66] (d 0..63, den at 64)
    float* pw = pout[w];
#pragma unroll
    for (int dt = 0; dt < 4; ++dt)
#pragma unroll
        for (int r = 0; r < 4; ++r)
            pw[((lane >> 4) * 4 + r) * 66 + dt * 16 + (lane & 15)] = accn[dt][r];
    if ((lane & 15) == 0) {
#pragma unroll
        for (int r = 0; r < 4; ++r)
            pw[((lane >> 4) * 4 + r) * 66 + 64] = accd[r];
    }
    __syncthreads();   // the only barrier: partials visible

    // ---------------- cross-wave reduction + epilogue ----------------
    {
        int i  = tid >> 5;         // 0..15
        int dd = tid & 31;         // d pair
        float s0 = 0.f, s1 = 0.f, dn = 0.f;
#pragma unroll
        for (int ww = 0; ww < 8; ++ww) {
            const float* pb = &pout[ww][i * 66];
            float2 v = *(const float2*)&pb[dd * 2];
            s0 += v.x; s1 += v.y; dn += pb[64];
        }
        float inv = 1.f / dn;
        float v0 = s0 * inv + bias[dd * 2];
        float v1 = s1 * inv + bias[dd * 2 + 1];
        float t0 = 1.f - 2.f / (__expf(2.f * v0) + 1.f);
        float t1 = 1.f - 2.f / (__expf(2.f * v1) + 1.f);
        float2 o = make_float2(t0, t1);
        *(float2*)&Hout[(size_t)(inst * NN + ib * 16 + i) * 64 + dd * 2] = o;
    }
}

// ---------------- mean-pool over nodes ----------------
__global__ __launch_bounds__(1024) void kpool(const float* __restrict__ H2, float* __restrict__ out)
{
    __shared__ float red[16][64];
    const int inst = blockIdx.x;
    const int tid = threadIdx.x, ig = tid >> 6, lane = tid & 63;
    float s = 0.f;
    for (int i = ig; i < NN; i += 16) s += H2[(size_t)(inst * NN + i) * 64 + lane];
    red[ig][lane] = s;
    __syncthreads();
    if (tid < 64) {
        float v = 0.f;
#pragma unroll
        for (int k = 0; k < 16; ++k) v += red[k][tid];
        out[inst * 64 + tid] = v * (1.f / NN);
    }
}

extern "C" void kernel_launch(void* const* d_in, const int* in_sizes, int n_in,
                              void* d_out, int out_size, void* d_ws, size_t ws_size,
                              hipStream_t stream)
{
    (void)in_sizes; (void)n_in; (void)out_size; (void)ws_size;
    const float* feat  = (const float*)d_in[0];
    const float* p1_Wl = (const float*)d_in[1],  *p1_Wr = (const float*)d_in[2];
    const float* p1_a  = (const float*)d_in[3],  *p1_b  = (const float*)d_in[4];
    const float* p2_Wl = (const float*)d_in[5],  *p2_Wr = (const float*)d_in[6];
    const float* p2_a  = (const float*)d_in[7],  *p2_b  = (const float*)d_in[8];
    const float* v1_Wl = (const float*)d_in[9],  *v1_Wr = (const float*)d_in[10];
    const float* v1_a  = (const float*)d_in[11], *v1_b  = (const float*)d_in[12];
    const float* v2_Wl = (const float*)d_in[13], *v2_Wr = (const float*)d_in[14];
    const float* v2_a  = (const float*)d_in[15], *v2_b  = (const float*)d_in[16];

    float* ws = (float*)d_ws;
    float* H1 = ws + OFF_H1;
    float* H2 = ws + OFF_H2;
    float* out = (float*)d_out;

    // layer 1 (input: features, K=128)
    kpre<128><<<dim3(64, 16), 256, 0, stream>>>(feat, 0, p1_Wl, p1_Wr, p1_a,
                                                v1_Wl, v1_Wr, v1_a, ws);
    kattn<<<dim3(32, 16), 512, 0, stream>>>(ws, p1_b, v1_b, H1);
    // layer 2 (input: H1, K=64)
    kpre<64><<<dim3(64, 16), 256, 0, stream>>>(H1, 1, p2_Wl, p2_Wr, p2_a,
                                               v2_Wl, v2_Wr, v2_a, ws);
    kattn<<<dim3(32, 16), 512, 0, stream>>>(ws, p2_b, v2_b, H2);
    // pool
    kpool<<<16, 1024, 0, stream>>>(H2, out);
}

// Round 7
// 89.779 us; speedup vs baseline: 1.3190x; 1.3190x over previous
//
#include <hip/hip_runtime.h>
#include <hip/hip_bf16.h>
#include <math.h>

#define NN 512
#define L2E 1.44269504089f
typedef __attribute__((ext_vector_type(8))) short short8;
typedef __attribute__((ext_vector_type(4))) float f32x4;
typedef _Float16 h2v __attribute__((ext_vector_type(2)));

// ws float offsets
#define OFF_XLI16 0u        // f16 xl interleaved: ushort[inst][jb8][q8][j64][d8]
#define OFF_XRH   262144u   // f16 xr rows: ushort[inst][row512][d64]
#define OFF_VV    524288u   // f32
#define OFF_SAH   532480u   // f16 sa: ushort[br][d64]
#define OFF_XLTH  532544u   // bf16 hi, transposed [inst][d][j]
#define OFF_XLTL  794688u   // bf16 lo
#define OFF_H1    1056832u
#define OFF_H2    1581120u

__device__ __forceinline__ float dterm(unsigned xr2, unsigned xl2, unsigned sa2, float acc)
{
#if __has_builtin(__builtin_amdgcn_fdot2)
    h2v z = __builtin_bit_cast(h2v, xr2) + __builtin_bit_cast(h2v, xl2);   // v_pk_add_f16
    unsigned az = __builtin_bit_cast(unsigned, z) & 0x7FFF7FFFu;           // dual abs
    return __builtin_amdgcn_fdot2(__builtin_bit_cast(h2v, az),
                                  __builtin_bit_cast(h2v, sa2), acc, false);
#else
    h2v z = __builtin_bit_cast(h2v, xr2) + __builtin_bit_cast(h2v, xl2);
    h2v s = __builtin_bit_cast(h2v, sa2);
    acc = fmaf((float)s[0], fabsf((float)z[0]), acc);
    return fmaf((float)s[1], fabsf((float)z[1]), acc);
#endif
}

// ---------------- GEMM + v/sa + f16 interleaved / f16 rows / bf16 transposed ----------------
template<int K>
__global__ __launch_bounds__(256) void kpre(
    const float* __restrict__ src, int srcPerInst,
    const float* __restrict__ Wl0, const float* __restrict__ Wr0, const float* __restrict__ a0,
    const float* __restrict__ Wl1, const float* __restrict__ Wr1, const float* __restrict__ a1,
    float* __restrict__ ws)
{
    __shared__ float xs[8 * K];
    const int rb   = blockIdx.x;   // 0..63 : 8-row block
    const int inst = blockIdx.y;   // 0..15 (br*8 + batch)
    const int br   = inst >> 3;
    const int tid  = threadIdx.x;
    const int d = tid & 63, ig = tid >> 6;
    const float* Wl = br ? Wl1 : Wl0;
    const float* Wr = br ? Wr1 : Wr0;
    const float* av = br ? a1  : a0;
    const float* sp = src + (size_t)(srcPerInst ? inst : (inst & 7)) * NN * K + (size_t)rb * 8 * K;

    if (tid < 2 * K) ((float4*)xs)[tid] = ((const float4*)sp)[tid];
    __syncthreads();

    float accl[2] = {0.f, 0.f}, accr[2] = {0.f, 0.f};
#pragma unroll 16
    for (int k = 0; k < K; ++k) {
        float wl = Wl[k * 64 + d];            // coalesced, L2-hot
        float wr = Wr[k * 64 + d];
#pragma unroll
        for (int rr = 0; rr < 2; ++rr) {
            float xv = xs[(ig * 2 + rr) * K + k];   // wave-uniform broadcast
            accl[rr] = fmaf(xv, wl, accl[rr]);
            accr[rr] = fmaf(xv, wr, accr[rr]);
        }
    }

    float aval = av[d];
    unsigned short* XLI = (unsigned short*)(ws + OFF_XLI16);
    unsigned short* XRH = (unsigned short*)(ws + OFF_XRH);
    unsigned short* SAH = (unsigned short*)(ws + OFF_SAH);
    float* VV = ws + OFF_VV;
    __hip_bfloat16* XLTH = (__hip_bfloat16*)(ws + OFF_XLTH);
    __hip_bfloat16* XLTL = (__hip_bfloat16*)(ws + OFF_XLTL);
#pragma unroll
    for (int rr = 0; rr < 2; ++rr) {
        int row = rb * 8 + ig * 2 + rr;
        // f16 xr row (for LDS staging in kattn)
        XRH[(size_t)(inst * NN + row) * 64 + d] =
            __builtin_bit_cast(unsigned short, (_Float16)accr[rr]);
        // f16 xl interleaved (per-lane coalesced row loads in kattn)
        XLI[((((size_t)inst * 8 + (row >> 6)) * 8 + (d >> 3)) * 64 + (row & 63)) * 8 + (d & 7)] =
            __builtin_bit_cast(unsigned short, (_Float16)accl[rr]);
        // transposed bf16 hi/lo for the MFMA B-operand
        __hip_bfloat16 h  = __float2bfloat16(accl[rr]);
        __hip_bfloat16 lo = __float2bfloat16(accl[rr] - __bfloat162float(h));
        size_t ot = (size_t)(inst * 64 + d) * NN + row;
        XLTH[ot] = h; XLTL[ot] = lo;
        float pv = aval * accl[rr];
#pragma unroll
        for (int mm = 32; mm > 0; mm >>= 1) pv += __shfl_xor(pv, mm, 64);
        if (d == 0) VV[inst * NN + row] = 0.6f * L2E * pv;   // log2e folded
    }
    if (rb == 0 && ig == 0 && (inst & 7) == 0)
        SAH[br * 64 + d] = __builtin_bit_cast(unsigned short, (_Float16)(0.4f * L2E * aval));
}

// ------- fused attention: f16 dot2 scoring (LDS-staged xr/sa), MFMA PV + den -------
__global__ __launch_bounds__(512, 4) void kattn(
    const float* __restrict__ ws,
    const float* __restrict__ b0, const float* __restrict__ b1,
    float* __restrict__ Hout)
{
    __shared__ __hip_bfloat16 pbuf[8][2048];   // per-wave p: 1024 hi + 1024 lo (32 KB)
    __shared__ float pout[8][1056];            // partial outs [w][i][66] (33 KB)
    __shared__ unsigned short xr_s[16 * 64];   // block's 16 xr rows, f16 (2 KB)
    __shared__ unsigned short sa_s[64];        // sa f16 (128 B)

    const int ib   = blockIdx.x;        // 0..31 : 16 i-rows
    const int inst = blockIdx.y;        // 0..15
    const int br   = inst >> 3;
    const int tid  = threadIdx.x;
    const int lane = tid & 63;
    const int w    = __builtin_amdgcn_readfirstlane(tid >> 6);   // wave id 0..7
    const float* VV = ws + OFF_VV + inst * NN;
    const __hip_bfloat16* XLTH = (const __hip_bfloat16*)(ws + OFF_XLTH) + (size_t)inst * 64 * NN;
    const __hip_bfloat16* XLTL = (const __hip_bfloat16*)(ws + OFF_XLTL) + (size_t)inst * 64 * NN;
    const float* bias = br ? b1 : b0;

    // stage xr rows (16 x 128B) + sa (128B) once
    {
        const unsigned short* XRH = (const unsigned short*)(ws + OFF_XRH) +
                                    ((size_t)inst * NN + ib * 16) * 64;
        if (tid < 128) ((uint4*)xr_s)[tid] = ((const uint4*)XRH)[tid];
        if (tid < 8)
            ((uint4*)sa_s)[tid] = ((const uint4*)((const unsigned short*)(ws + OFF_SAH) + br * 64))[tid];
    }

    // per-lane xl row (j = w*64+lane) as f16 pairs, coalesced; 8 x uint4
    unsigned xl2[32];
    {
        const uint4* xli = (const uint4*)(ws + OFF_XLI16) + ((size_t)inst * 8 + w) * 8 * 64;
#pragma unroll
        for (int q8 = 0; q8 < 8; ++q8) {
            uint4 v = xli[q8 * 64 + lane];
            xl2[q8*4+0] = v.x; xl2[q8*4+1] = v.y; xl2[q8*4+2] = v.z; xl2[q8*4+3] = v.w;
        }
    }
    float vj = VV[w * 64 + lane];
    __syncthreads();   // b1: xr/sa staged

    // ---------------- scoring: e[16] via pk_add + and-abs + dot2 ----------------
    float e[16];
#pragma unroll
    for (int ii = 0; ii < 16; ++ii) e[ii] = 0.f;
    const uint4* xr4 = (const uint4*)xr_s;     // 8 chunks per row
    const uint4* sa4 = (const uint4*)sa_s;
#pragma unroll
    for (int q8 = 0; q8 < 8; ++q8) {
        uint4 s4 = sa4[q8];                    // broadcast b128
#pragma unroll
        for (int ii = 0; ii < 16; ++ii) {
            uint4 r4 = xr4[ii * 8 + q8];       // broadcast b128
            float t = dterm(r4.x, xl2[q8*4+0], s4.x, e[ii]);
            t = dterm(r4.y, xl2[q8*4+1], s4.y, t);
            t = dterm(r4.z, xl2[q8*4+2], s4.z, t);
            e[ii] = dterm(r4.w, xl2[q8*4+3], s4.w, t);
        }
    }

    // ---------------- p = exp2, bf16 hi/lo, wave-private transpose in LDS ----------------
    __hip_bfloat16* phw = pbuf[w];
    __hip_bfloat16* plw = pbuf[w] + 1024;
#pragma unroll
    for (int ii = 0; ii < 16; ++ii) {
        float p = exp2f(e[ii] + vj);
        __hip_bfloat16 h  = __float2bfloat16(p);
        __hip_bfloat16 lo = __float2bfloat16(p - __bfloat162float(h));
        int idx = ii * 64 + (((lane >> 3) ^ (ii & 7)) << 3) + (lane & 7);
        phw[idx] = h; plw[idx] = lo;
    }

    // ---------------- PV + den via MFMA (wave-private A-frags) ----------------
    f32x4 accn[4] = {{0,0,0,0},{0,0,0,0},{0,0,0,0},{0,0,0,0}};
    f32x4 accd = {0, 0, 0, 0};
    const short8 ones = {16256,16256,16256,16256,16256,16256,16256,16256};  // bf16 1.0
#pragma unroll
    for (int ks = 0; ks < 2; ++ks) {
        int aidx = (lane & 15) * 64 + ((((ks << 2) + (lane >> 4)) ^ (lane & 7)) << 3);
        short8 ah = *(const short8*)&phw[aidx];
        short8 al = *(const short8*)&plw[aidx];
        int jb = w * 64 + ks * 32 + (lane >> 4) * 8;
#pragma unroll
        for (int dt = 0; dt < 4; ++dt) {
            float4 bhv = *(const float4*)&XLTH[(size_t)(dt * 16 + (lane & 15)) * NN + jb];
            float4 blv = *(const float4*)&XLTL[(size_t)(dt * 16 + (lane & 15)) * NN + jb];
            short8 bh = __builtin_bit_cast(short8, bhv);
            short8 bl = __builtin_bit_cast(short8, blv);
            accn[dt] = __builtin_amdgcn_mfma_f32_16x16x32_bf16(ah, bh, accn[dt], 0, 0, 0);
            accn[dt] = __builtin_amdgcn_mfma_f32_16x16x32_bf16(al, bh, accn[dt], 0, 0, 0);
            accn[dt] = __builtin_amdgcn_mfma_f32_16x16x32_bf16(ah, bl, accn[dt], 0, 0, 0);
        }
        accd = __builtin_amdgcn_mfma_f32_16x16x32_bf16(ah, ones, accd, 0, 0, 0);
        accd = __builtin_amdgcn_mfma_f32_16x16x32_bf16(al, ones, accd, 0, 0, 0);
    }

    // partial outs -> LDS: pout[w][i][66] (d 0..63, den at 64)
    float* pw = pout[w];
#pragma unroll
    for (int dt = 0; dt < 4; ++dt)
#pragma unroll
        for (int r = 0; r < 4; ++r)
            pw[((lane >> 4) * 4 + r) * 66 + dt * 16 + (lane & 15)] = accn[dt][r];
    if ((lane & 15) == 0) {
#pragma unroll
        for (int r = 0; r < 4; ++r)
            pw[((lane >> 4) * 4 + r) * 66 + 64] = accd[r];
    }
    __syncthreads();   // b2: partials visible

    // ---------------- cross-wave reduction + epilogue ----------------
    {
        int i  = tid >> 5;         // 0..15
        int dd = tid & 31;         // d pair
        float s0 = 0.f, s1 = 0.f, dn = 0.f;
#pragma unroll
        for (int ww = 0; ww < 8; ++ww) {
            const float* pb = &pout[ww][i * 66];
            float2 v = *(const float2*)&pb[dd * 2];
            s0 += v.x; s1 += v.y; dn += pb[64];
        }
        float inv = 1.f / dn;
        float v0 = s0 * inv + bias[dd * 2];
        float v1 = s1 * inv + bias[dd * 2 + 1];
        float t0 = 1.f - 2.f / (__expf(2.f * v0) + 1.f);
        float t1 = 1.f - 2.f / (__expf(2.f * v1) + 1.f);
        float2 o = make_float2(t0, t1);
        *(float2*)&Hout[(size_t)(inst * NN + ib * 16 + i) * 64 + dd * 2] = o;
    }
}

// ---------------- mean-pool over nodes ----------------
__global__ __launch_bounds__(1024) void kpool(const float* __restrict__ H2, float* __restrict__ out)
{
    __shared__ float red[16][64];
    const int inst = blockIdx.x;
    const int tid = threadIdx.x, ig = tid >> 6, lane = tid & 63;
    float s = 0.f;
    for (int i = ig; i < NN; i += 16) s += H2[(size_t)(inst * NN + i) * 64 + lane];
    red[ig][lane] = s;
    __syncthreads();
    if (tid < 64) {
        float v = 0.f;
#pragma unroll
        for (int k = 0; k < 16; ++k) v += red[k][tid];
        out[inst * 64 + tid] = v * (1.f / NN);
    }
}

extern "C" void kernel_launch(void* const* d_in, const int* in_sizes, int n_in,
                              void* d_out, int out_size, void* d_ws, size_t ws_size,
                              hipStream_t stream)
{
    (void)in_sizes; (void)n_in; (void)out_size; (void)ws_size;
    const float* feat  = (const float*)d_in[0];
    const float* p1_Wl = (const float*)d_in[1],  *p1_Wr = (const float*)d_in[2];
    const float* p1_a  = (const float*)d_in[3],  *p1_b  = (const float*)d_in[4];
    const float* p2_Wl = (const float*)d_in[5],  *p2_Wr = (const float*)d_in[6];
    const float* p2_a  = (const float*)d_in[7],  *p2_b  = (const float*)d_in[8];
    const float* v1_Wl = (const float*)d_in[9],  *v1_Wr = (const float*)d_in[10];
    const float* v1_a  = (const float*)d_in[11], *v1_b  = (const float*)d_in[12];
    const float* v2_Wl = (const float*)d_in[13], *v2_Wr = (const float*)d_in[14];
    const float* v2_a  = (const float*)d_in[15], *v2_b  = (const float*)d_in[16];

    float* ws = (float*)d_ws;
    float* H1 = ws + OFF_H1;
    float* H2 = ws + OFF_H2;
    float* out = (float*)d_out;

    // layer 1 (input: features, K=128)
    kpre<128><<<dim3(64, 16), 256, 0, stream>>>(feat, 0, p1_Wl, p1_Wr, p1_a,
                                                v1_Wl, v1_Wr, v1_a, ws);
    kattn<<<dim3(32, 16), 512, 0, stream>>>(ws, p1_b, v1_b, H1);
    // layer 2 (input: H1, K=64)
    kpre<64><<<dim3(64, 16), 256, 0, stream>>>(H1, 1, p2_Wl, p2_Wr, p2_a,
                                               v2_Wl, v2_Wr, v2_a, ws);
    kattn<<<dim3(32, 16), 512, 0, stream>>>(ws, p2_b, v2_b, H2);
    // pool
    kpool<<<16, 1024, 0, stream>>>(H2, out);
}

// Round 8
// 68.485 us; speedup vs baseline: 1.7292x; 1.3109x over previous
//
#include <hip/hip_runtime.h>
#include <hip/hip_bf16.h>
#include <math.h>

#define NN 512
#define L2E 1.44269504089f
typedef __attribute__((ext_vector_type(4))) float f32x4;
typedef _Float16 h2v __attribute__((ext_vector_type(2)));
typedef _Float16 h8  __attribute__((ext_vector_type(8)));

// ws float offsets
#define OFF_XLI  0u         // f16 xl interleaved: ushort[inst][jb8][q8][j64][d8]
#define OFF_XRH  262144u    // f16 xr rows: ushort[inst][row512][d64]
#define OFF_VV   524288u    // f32
#define OFF_SAH  532480u    // f16 sa
#define OFF_XLTF 532608u    // f16 xl transposed [inst][d64][j512]
#define OFF_H1   794752u    // f32 H1

__device__ __forceinline__ float dterm(unsigned xr2, unsigned xl2, unsigned sa2, float acc)
{
#if __has_builtin(__builtin_amdgcn_fdot2)
    h2v z = __builtin_bit_cast(h2v, xr2) + __builtin_bit_cast(h2v, xl2);   // v_pk_add_f16
    unsigned az = __builtin_bit_cast(unsigned, z) & 0x7FFF7FFFu;           // dual abs
    return __builtin_amdgcn_fdot2(__builtin_bit_cast(h2v, az),
                                  __builtin_bit_cast(h2v, sa2), acc, false);
#else
    h2v z = __builtin_bit_cast(h2v, xr2) + __builtin_bit_cast(h2v, xl2);
    h2v s = __builtin_bit_cast(h2v, sa2);
    acc = fmaf((float)s[0], fabsf((float)z[0]), acc);
    return fmaf((float)s[1], fabsf((float)z[1]), acc);
#endif
}

// ---------------- GEMM + v/sa + f16 interleaved / rows / transposed ----------------
template<int K>
__global__ __launch_bounds__(256) void kpre(
    const float* __restrict__ src, int srcPerInst,
    const float* __restrict__ Wl0, const float* __restrict__ Wr0, const float* __restrict__ a0,
    const float* __restrict__ Wl1, const float* __restrict__ Wr1, const float* __restrict__ a1,
    float* __restrict__ ws)
{
    __shared__ float xs[16 * K];
    const int rb   = blockIdx.x;   // 0..31 : 16-row block
    const int inst = blockIdx.y;   // 0..15 (br*8 + batch)
    const int br   = inst >> 3;
    const int tid  = threadIdx.x;
    const int d = tid & 63, ig = tid >> 6;
    const float* Wl = br ? Wl1 : Wl0;
    const float* Wr = br ? Wr1 : Wr0;
    const float* av = br ? a1  : a0;
    const float* sp = src + (size_t)(srcPerInst ? inst : (inst & 7)) * NN * K + (size_t)rb * 16 * K;

    for (int i = tid; i < 4 * K; i += 256) ((float4*)xs)[i] = ((const float4*)sp)[i];
    __syncthreads();

    float accl[4] = {0.f,0.f,0.f,0.f}, accr[4] = {0.f,0.f,0.f,0.f};
#pragma unroll 4
    for (int k4 = 0; k4 < K / 4; ++k4) {
        float xcv[4][4];
#pragma unroll
        for (int rr = 0; rr < 4; ++rr) {
            float4 v = ((const float4*)xs)[(ig * 4 + rr) * (K / 4) + k4];
            xcv[rr][0] = v.x; xcv[rr][1] = v.y; xcv[rr][2] = v.z; xcv[rr][3] = v.w;
        }
#pragma unroll
        for (int e = 0; e < 4; ++e) {
            float wl = Wl[(k4 * 4 + e) * 64 + d];   // coalesced, L1/L2-hot
            float wr = Wr[(k4 * 4 + e) * 64 + d];
#pragma unroll
            for (int rr = 0; rr < 4; ++rr) {
                accl[rr] = fmaf(xcv[rr][e], wl, accl[rr]);
                accr[rr] = fmaf(xcv[rr][e], wr, accr[rr]);
            }
        }
    }

    float aval = av[d];
    unsigned short* XLI  = (unsigned short*)(ws + OFF_XLI);
    unsigned short* XRH  = (unsigned short*)(ws + OFF_XRH);
    unsigned short* SAH  = (unsigned short*)(ws + OFF_SAH);
    unsigned short* XLTF = (unsigned short*)(ws + OFF_XLTF);
    float* VV = ws + OFF_VV;
#pragma unroll
    for (int rr = 0; rr < 4; ++rr) {
        int row = rb * 16 + ig * 4 + rr;
        XRH[(size_t)(inst * NN + row) * 64 + d] =
            __builtin_bit_cast(unsigned short, (_Float16)accr[rr]);
        XLI[((((size_t)inst * 8 + (row >> 6)) * 8 + (d >> 3)) * 64 + (row & 63)) * 8 + (d & 7)] =
            __builtin_bit_cast(unsigned short, (_Float16)accl[rr]);
        XLTF[(size_t)(inst * 64 + d) * NN + row] =
            __builtin_bit_cast(unsigned short, (_Float16)accl[rr]);
        float pv = aval * accl[rr];
#pragma unroll
        for (int mm = 32; mm > 0; mm >>= 1) pv += __shfl_xor(pv, mm, 64);
        if (d == 0) VV[inst * NN + row] = 0.6f * L2E * pv;   // log2e folded
    }
    if (rb == 0 && ig == 0 && (inst & 7) == 0)
        SAH[br * 64 + d] = __builtin_bit_cast(unsigned short, (_Float16)(0.4f * L2E * aval));
}

// ------- fused attention: f16 dot2 scoring, f16 MFMA PV + den; LAYER2 fuses mean-pool -------
template<int LAYER>
__global__ __launch_bounds__(512, 4) void kattn(
    const float* __restrict__ ws,
    const float* __restrict__ b0, const float* __restrict__ b1,
    float* __restrict__ Hout)
{
    __shared__ unsigned short pbuf[8][1024];   // per-wave p (f16), 16 KB
    __shared__ float pout[8][1056];            // partial outs [w][i][66], 33 KB
    __shared__ unsigned short xr_s[16 * 64];   // 16 xr rows f16 (2 KB); reused as poolbuf
    __shared__ unsigned short sa_s[64];

    const int ib   = blockIdx.x;        // 0..31 : 16 i-rows
    const int inst = blockIdx.y;        // 0..15
    const int br   = inst >> 3;
    const int tid  = threadIdx.x;
    const int lane = tid & 63;
    const int w    = __builtin_amdgcn_readfirstlane(tid >> 6);   // wave id 0..7
    const float* VV = ws + OFF_VV + inst * NN;
    const unsigned short* XLTF = (const unsigned short*)(ws + OFF_XLTF) + (size_t)inst * 64 * NN;
    const float* bias = br ? b1 : b0;

    // stage xr rows + sa once
    {
        const unsigned short* XRH = (const unsigned short*)(ws + OFF_XRH) +
                                    ((size_t)inst * NN + ib * 16) * 64;
        if (tid < 128) ((uint4*)xr_s)[tid] = ((const uint4*)XRH)[tid];
        if (tid < 8)
            ((uint4*)sa_s)[tid] = ((const uint4*)((const unsigned short*)(ws + OFF_SAH) + br * 64))[tid];
    }

    // per-lane xl row (j = w*64+lane) as f16 pairs; 8 x uint4, coalesced
    unsigned xl2[32];
    {
        const uint4* xli = (const uint4*)(ws + OFF_XLI) + ((size_t)inst * 8 + w) * 8 * 64;
#pragma unroll
        for (int q8 = 0; q8 < 8; ++q8) {
            uint4 v = xli[q8 * 64 + lane];
            xl2[q8*4+0] = v.x; xl2[q8*4+1] = v.y; xl2[q8*4+2] = v.z; xl2[q8*4+3] = v.w;
        }
    }
    float vj = VV[w * 64 + lane];
    __syncthreads();   // b1: xr/sa staged

    // ---------------- scoring: e[16] via pk_add + and-abs + dot2 ----------------
    float e[16];
#pragma unroll
    for (int ii = 0; ii < 16; ++ii) e[ii] = 0.f;
    const uint4* xr4 = (const uint4*)xr_s;
    const uint4* sa4 = (const uint4*)sa_s;
#pragma unroll
    for (int q8 = 0; q8 < 8; ++q8) {
        uint4 s4 = sa4[q8];                    // broadcast b128
#pragma unroll
        for (int ii = 0; ii < 16; ++ii) {
            uint4 r4 = xr4[ii * 8 + q8];       // broadcast b128
            float t = dterm(r4.x, xl2[q8*4+0], s4.x, e[ii]);
            t = dterm(r4.y, xl2[q8*4+1], s4.y, t);
            t = dterm(r4.z, xl2[q8*4+2], s4.z, t);
            e[ii] = dterm(r4.w, xl2[q8*4+3], s4.w, t);
        }
    }

    // B-operand loads (L2-hot); latency hidden under p-split + pbuf round-trip
    float4 bv[8];
#pragma unroll
    for (int ks = 0; ks < 2; ++ks)
#pragma unroll
        for (int dt = 0; dt < 4; ++dt)
            bv[ks*4+dt] = *(const float4*)&XLTF[(size_t)(dt * 16 + (lane & 15)) * NN +
                                                w * 64 + ks * 32 + (lane >> 4) * 8];

    // ---------------- p = exp2 (f16), wave-private swizzled transpose in LDS ----------------
    unsigned short* phw = pbuf[w];
#pragma unroll
    for (int ii = 0; ii < 16; ++ii) {
        float p = exp2f(e[ii] + vj);           // p bounded ~2^10, f16-safe
        int idx = ii * 64 + (((lane >> 3) ^ (ii & 7)) << 3) + (lane & 7);
        phw[idx] = __builtin_bit_cast(unsigned short, (_Float16)p);
    }

    // ---------------- PV + den via f16 MFMA (wave-private A-frags) ----------------
    f32x4 accn[4] = {{0,0,0,0},{0,0,0,0},{0,0,0,0},{0,0,0,0}};
    f32x4 accd = {0, 0, 0, 0};
    const h8 ones = {(_Float16)1.f,(_Float16)1.f,(_Float16)1.f,(_Float16)1.f,
                     (_Float16)1.f,(_Float16)1.f,(_Float16)1.f,(_Float16)1.f};
#pragma unroll
    for (int ks = 0; ks < 2; ++ks) {
        int aidx = (lane & 15) * 64 + ((((ks << 2) + (lane >> 4)) ^ (lane & 7)) << 3);
        h8 a = *(const h8*)&phw[aidx];
#pragma unroll
        for (int dt = 0; dt < 4; ++dt)
            accn[dt] = __builtin_amdgcn_mfma_f32_16x16x32_f16(
                a, __builtin_bit_cast(h8, bv[ks*4+dt]), accn[dt], 0, 0, 0);
        accd = __builtin_amdgcn_mfma_f32_16x16x32_f16(a, ones, accd, 0, 0, 0);
    }

    // partial outs -> LDS: pout[w][i][66] (d 0..63, den at 64)
    float* pw = pout[w];
#pragma unroll
    for (int dt = 0; dt < 4; ++dt)
#pragma unroll
        for (int r = 0; r < 4; ++r)
            pw[((lane >> 4) * 4 + r) * 66 + dt * 16 + (lane & 15)] = accn[dt][r];
    if ((lane & 15) == 0) {
#pragma unroll
        for (int r = 0; r < 4; ++r)
            pw[((lane >> 4) * 4 + r) * 66 + 64] = accd[r];
    }
    __syncthreads();   // b2: partials visible (xr_s dead after this)

    // ---------------- cross-wave reduction + epilogue ----------------
    const int i  = tid >> 5;         // 0..15
    const int dd = tid & 31;         // d pair
    float s0 = 0.f, s1 = 0.f, dn = 0.f;
#pragma unroll
    for (int ww = 0; ww < 8; ++ww) {
        const float* pb = &pout[ww][i * 66];
        float2 v = *(const float2*)&pb[dd * 2];
        s0 += v.x; s1 += v.y; dn += pb[64];
    }
    float inv = 1.f / dn;
    float v0 = s0 * inv + bias[dd * 2];
    float v1 = s1 * inv + bias[dd * 2 + 1];
    float t0 = 1.f - 2.f / (__expf(2.f * v0) + 1.f);   // tanh
    float t1 = 1.f - 2.f / (__expf(2.f * v1) + 1.f);

    if (LAYER == 1) {
        *(float2*)&Hout[(size_t)(inst * NN + ib * 16 + i) * 64 + dd * 2] = make_float2(t0, t1);
    } else {
        // fused mean-pool: wave pair-sum over its 2 i-rows, block reduce, one atomic per d
        float s0p = t0 + __shfl_xor(t0, 32, 64);
        float s1p = t1 + __shfl_xor(t1, 32, 64);
        float* poolbuf = (float*)xr_s;            // 8*64 f32 = 2 KB, xr_s is dead
        if (lane < 32) {
            poolbuf[w * 64 + dd * 2]     = s0p;
            poolbuf[w * 64 + dd * 2 + 1] = s1p;
        }
        __syncthreads();
        if (tid < 64) {
            float s = 0.f;
#pragma unroll
            for (int ww = 0; ww < 8; ++ww) s += poolbuf[ww * 64 + tid];
            atomicAdd(&Hout[inst * 64 + tid], s * (1.f / NN));
        }
    }
}

extern "C" void kernel_launch(void* const* d_in, const int* in_sizes, int n_in,
                              void* d_out, int out_size, void* d_ws, size_t ws_size,
                              hipStream_t stream)
{
    (void)in_sizes; (void)n_in; (void)ws_size;
    const float* feat  = (const float*)d_in[0];
    const float* p1_Wl = (const float*)d_in[1],  *p1_Wr = (const float*)d_in[2];
    const float* p1_a  = (const float*)d_in[3],  *p1_b  = (const float*)d_in[4];
    const float* p2_Wl = (const float*)d_in[5],  *p2_Wr = (const float*)d_in[6];
    const float* p2_a  = (const float*)d_in[7],  *p2_b  = (const float*)d_in[8];
    const float* v1_Wl = (const float*)d_in[9],  *v1_Wr = (const float*)d_in[10];
    const float* v1_a  = (const float*)d_in[11], *v1_b  = (const float*)d_in[12];
    const float* v2_Wl = (const float*)d_in[13], *v2_Wr = (const float*)d_in[14];
    const float* v2_a  = (const float*)d_in[15], *v2_b  = (const float*)d_in[16];

    float* ws = (float*)d_ws;
    float* H1 = ws + OFF_H1;
    float* out = (float*)d_out;

    // zero the pooled output (accumulated via atomics in kattn<2>)
    hipMemsetAsync(out, 0, (size_t)out_size * sizeof(float), stream);

    // layer 1 (input: features, K=128)
    kpre<128><<<dim3(32, 16), 256, 0, stream>>>(feat, 0, p1_Wl, p1_Wr, p1_a,
                                                v1_Wl, v1_Wr, v1_a, ws);
    kattn<1><<<dim3(32, 16), 512, 0, stream>>>(ws, p1_b, v1_b, H1);
    // layer 2 (input: H1, K=64) + fused mean-pool
    kpre<64><<<dim3(32, 16), 256, 0, stream>>>(H1, 1, p2_Wl, p2_Wr, p2_a,
                                               v2_Wl, v2_Wr, v2_a, ws);
    kattn<2><<<dim3(32, 16), 512, 0, stream>>>(ws, p2_b, v2_b, out);
}

// Round 9
// 65.553 us; speedup vs baseline: 1.8065x; 1.0447x over previous
//
#include <hip/hip_runtime.h>
#include <hip/hip_bf16.h>
#include <math.h>

#define NN 512
#define L2E 1.44269504089f
typedef __attribute__((ext_vector_type(4))) float f32x4;
typedef _Float16 h2v __attribute__((ext_vector_type(2)));
typedef _Float16 h8  __attribute__((ext_vector_type(8)));

// ws float offsets
#define OFF_XLI  0u         // f16 xl interleaved: ushort[inst][jb8][q8][j64][d8]
#define OFF_XRH  262144u    // f16 xr rows: ushort[inst][row512][d64]
#define OFF_VV   524288u    // f32
#define OFF_SAH  532480u    // f16 sa
#define OFF_XLTF 532608u    // f16 xl transposed [inst][d64][j512]
#define OFF_H1   794752u    // f32 H1 (16*512*64)
#define OFF_POOL 1319040u   // f32 pool partials [inst16][ib32][64]

__device__ __forceinline__ float dterm(unsigned xr2, unsigned xl2, unsigned sa2, float acc)
{
#if __has_builtin(__builtin_amdgcn_fdot2)
    h2v z = __builtin_bit_cast(h2v, xr2) + __builtin_bit_cast(h2v, xl2);   // v_pk_add_f16
    unsigned az = __builtin_bit_cast(unsigned, z) & 0x7FFF7FFFu;           // dual abs
    return __builtin_amdgcn_fdot2(__builtin_bit_cast(h2v, az),
                                  __builtin_bit_cast(h2v, sa2), acc, false);
#else
    h2v z = __builtin_bit_cast(h2v, xr2) + __builtin_bit_cast(h2v, xl2);
    h2v s = __builtin_bit_cast(h2v, sa2);
    acc = fmaf((float)s[0], fabsf((float)z[0]), acc);
    return fmaf((float)s[1], fabsf((float)z[1]), acc);
#endif
}

// ---------------- GEMM + v/sa + f16 interleaved / rows / transposed ----------------
template<int K>
__global__ __launch_bounds__(256) void kpre(
    const float* __restrict__ src, int srcPerInst,
    const float* __restrict__ Wl0, const float* __restrict__ Wr0, const float* __restrict__ a0,
    const float* __restrict__ Wl1, const float* __restrict__ Wr1, const float* __restrict__ a1,
    float* __restrict__ ws)
{
    __shared__ float xs[16 * K];
    const int rb   = blockIdx.x;   // 0..31 : 16-row block
    const int inst = blockIdx.y;   // 0..15 (br*8 + batch)
    const int br   = inst >> 3;
    const int tid  = threadIdx.x;
    const int d = tid & 63, ig = tid >> 6;
    const float* Wl = br ? Wl1 : Wl0;
    const float* Wr = br ? Wr1 : Wr0;
    const float* av = br ? a1  : a0;
    const float* sp = src + (size_t)(srcPerInst ? inst : (inst & 7)) * NN * K + (size_t)rb * 16 * K;

    for (int i = tid; i < 4 * K; i += 256) ((float4*)xs)[i] = ((const float4*)sp)[i];
    __syncthreads();

    float accl[4] = {0.f,0.f,0.f,0.f}, accr[4] = {0.f,0.f,0.f,0.f};
#pragma unroll 4
    for (int k4 = 0; k4 < K / 4; ++k4) {
        float xcv[4][4];
#pragma unroll
        for (int rr = 0; rr < 4; ++rr) {
            float4 v = ((const float4*)xs)[(ig * 4 + rr) * (K / 4) + k4];
            xcv[rr][0] = v.x; xcv[rr][1] = v.y; xcv[rr][2] = v.z; xcv[rr][3] = v.w;
        }
#pragma unroll
        for (int e = 0; e < 4; ++e) {
            float wl = Wl[(k4 * 4 + e) * 64 + d];   // coalesced, L1/L2-hot
            float wr = Wr[(k4 * 4 + e) * 64 + d];
#pragma unroll
            for (int rr = 0; rr < 4; ++rr) {
                accl[rr] = fmaf(xcv[rr][e], wl, accl[rr]);
                accr[rr] = fmaf(xcv[rr][e], wr, accr[rr]);
            }
        }
    }

    float aval = av[d];
    unsigned short* XLI  = (unsigned short*)(ws + OFF_XLI);
    unsigned short* XRH  = (unsigned short*)(ws + OFF_XRH);
    unsigned short* SAH  = (unsigned short*)(ws + OFF_SAH);
    unsigned short* XLTF = (unsigned short*)(ws + OFF_XLTF);
    float* VV = ws + OFF_VV;
#pragma unroll
    for (int rr = 0; rr < 4; ++rr) {
        int row = rb * 16 + ig * 4 + rr;
        XRH[(size_t)(inst * NN + row) * 64 + d] =
            __builtin_bit_cast(unsigned short, (_Float16)accr[rr]);
        XLI[((((size_t)inst * 8 + (row >> 6)) * 8 + (d >> 3)) * 64 + (row & 63)) * 8 + (d & 7)] =
            __builtin_bit_cast(unsigned short, (_Float16)accl[rr]);
        XLTF[(size_t)(inst * 64 + d) * NN + row] =
            __builtin_bit_cast(unsigned short, (_Float16)accl[rr]);
        float pv = aval * accl[rr];
#pragma unroll
        for (int mm = 32; mm > 0; mm >>= 1) pv += __shfl_xor(pv, mm, 64);
        if (d == 0) VV[inst * NN + row] = 0.6f * L2E * pv;   // log2e folded
    }
    if (rb == 0 && ig == 0 && (inst & 7) == 0)
        SAH[br * 64 + d] = __builtin_bit_cast(unsigned short, (_Float16)(0.4f * L2E * aval));
}

// ------- fused attention: f16 dot2 scoring, f16 MFMA PV + den; LAYER2 writes pool partials -------
template<int LAYER>
__global__ __launch_bounds__(512, 4) void kattn(
    const float* __restrict__ ws,
    const float* __restrict__ b0, const float* __restrict__ b1,
    float* __restrict__ Hout)
{
    __shared__ unsigned short pbuf[8][1024];   // per-wave p (f16), 16 KB
    __shared__ float pout[8][1056];            // partial outs [w][i][66], 33 KB
    __shared__ unsigned short xr_s[16 * 64];   // 16 xr rows f16 (2 KB); reused as poolbuf
    __shared__ unsigned short sa_s[64];

    const int ib   = blockIdx.x;        // 0..31 : 16 i-rows
    const int inst = blockIdx.y;        // 0..15
    const int br   = inst >> 3;
    const int tid  = threadIdx.x;
    const int lane = tid & 63;
    const int w    = __builtin_amdgcn_readfirstlane(tid >> 6);   // wave id 0..7
    const float* VV = ws + OFF_VV + inst * NN;
    const unsigned short* XLTF = (const unsigned short*)(ws + OFF_XLTF) + (size_t)inst * 64 * NN;
    const float* bias = br ? b1 : b0;

    // stage xr rows + sa once
    {
        const unsigned short* XRH = (const unsigned short*)(ws + OFF_XRH) +
                                    ((size_t)inst * NN + ib * 16) * 64;
        if (tid < 128) ((uint4*)xr_s)[tid] = ((const uint4*)XRH)[tid];
        if (tid < 8)
            ((uint4*)sa_s)[tid] = ((const uint4*)((const unsigned short*)(ws + OFF_SAH) + br * 64))[tid];
    }

    // per-lane xl row (j = w*64+lane) as f16 pairs; 8 x uint4, coalesced
    unsigned xl2[32];
    {
        const uint4* xli = (const uint4*)(ws + OFF_XLI) + ((size_t)inst * 8 + w) * 8 * 64;
#pragma unroll
        for (int q8 = 0; q8 < 8; ++q8) {
            uint4 v = xli[q8 * 64 + lane];
            xl2[q8*4+0] = v.x; xl2[q8*4+1] = v.y; xl2[q8*4+2] = v.z; xl2[q8*4+3] = v.w;
        }
    }
    float vj = VV[w * 64 + lane];
    __syncthreads();   // b1: xr/sa staged

    // ---------------- scoring: e[16] via pk_add + and-abs + dot2 ----------------
    float e[16];
#pragma unroll
    for (int ii = 0; ii < 16; ++ii) e[ii] = 0.f;
    const uint4* xr4 = (const uint4*)xr_s;
    const uint4* sa4 = (const uint4*)sa_s;
#pragma unroll
    for (int q8 = 0; q8 < 8; ++q8) {
        uint4 s4 = sa4[q8];                    // broadcast b128
#pragma unroll
        for (int ii = 0; ii < 16; ++ii) {
            uint4 r4 = xr4[ii * 8 + q8];       // broadcast b128
            float t = dterm(r4.x, xl2[q8*4+0], s4.x, e[ii]);
            t = dterm(r4.y, xl2[q8*4+1], s4.y, t);
            t = dterm(r4.z, xl2[q8*4+2], s4.z, t);
            e[ii] = dterm(r4.w, xl2[q8*4+3], s4.w, t);
        }
    }

    // B-operand loads (L2-hot); latency hidden under p-split + pbuf round-trip
    float4 bv[8];
#pragma unroll
    for (int ks = 0; ks < 2; ++ks)
#pragma unroll
        for (int dt = 0; dt < 4; ++dt)
            bv[ks*4+dt] = *(const float4*)&XLTF[(size_t)(dt * 16 + (lane & 15)) * NN +
                                                w * 64 + ks * 32 + (lane >> 4) * 8];

    // ---------------- p = exp2 (f16), wave-private swizzled transpose in LDS ----------------
    unsigned short* phw = pbuf[w];
#pragma unroll
    for (int ii = 0; ii < 16; ++ii) {
        float p = exp2f(e[ii] + vj);           // p bounded ~2^10, f16-safe
        int idx = ii * 64 + (((lane >> 3) ^ (ii & 7)) << 3) + (lane & 7);
        phw[idx] = __builtin_bit_cast(unsigned short, (_Float16)p);
    }

    // ---------------- PV + den via f16 MFMA (wave-private A-frags) ----------------
    f32x4 accn[4] = {{0,0,0,0},{0,0,0,0},{0,0,0,0},{0,0,0,0}};
    f32x4 accd = {0, 0, 0, 0};
    const h8 ones = {(_Float16)1.f,(_Float16)1.f,(_Float16)1.f,(_Float16)1.f,
                     (_Float16)1.f,(_Float16)1.f,(_Float16)1.f,(_Float16)1.f};
#pragma unroll
    for (int ks = 0; ks < 2; ++ks) {
        int aidx = (lane & 15) * 64 + ((((ks << 2) + (lane >> 4)) ^ (lane & 7)) << 3);
        h8 a = *(const h8*)&phw[aidx];
#pragma unroll
        for (int dt = 0; dt < 4; ++dt)
            accn[dt] = __builtin_amdgcn_mfma_f32_16x16x32_f16(
                a, __builtin_bit_cast(h8, bv[ks*4+dt]), accn[dt], 0, 0, 0);
        accd = __builtin_amdgcn_mfma_f32_16x16x32_f16(a, ones, accd, 0, 0, 0);
    }

    // partial outs -> LDS: pout[w][i][66] (d 0..63, den at 64)
    float* pw = pout[w];
#pragma unroll
    for (int dt = 0; dt < 4; ++dt)
#pragma unroll
        for (int r = 0; r < 4; ++r)
            pw[((lane >> 4) * 4 + r) * 66 + dt * 16 + (lane & 15)] = accn[dt][r];
    if ((lane & 15) == 0) {
#pragma unroll
        for (int r = 0; r < 4; ++r)
            pw[((lane >> 4) * 4 + r) * 66 + 64] = accd[r];
    }
    __syncthreads();   // b2: partials visible (xr_s dead after this)

    // ---------------- cross-wave reduction + epilogue ----------------
    const int i  = tid >> 5;         // 0..15
    const int dd = tid & 31;         // d pair
    float s0 = 0.f, s1 = 0.f, dn = 0.f;
#pragma unroll
    for (int ww = 0; ww < 8; ++ww) {
        const float* pb = &pout[ww][i * 66];
        float2 v = *(const float2*)&pb[dd * 2];
        s0 += v.x; s1 += v.y; dn += pb[64];
    }
    float inv = 1.f / dn;
    float v0 = s0 * inv + bias[dd * 2];
    float v1 = s1 * inv + bias[dd * 2 + 1];
    float t0 = 1.f - 2.f / (__expf(2.f * v0) + 1.f);   // tanh
    float t1 = 1.f - 2.f / (__expf(2.f * v1) + 1.f);

    if (LAYER == 1) {
        *(float2*)&Hout[(size_t)(inst * NN + ib * 16 + i) * 64 + dd * 2] = make_float2(t0, t1);
    } else {
        // fused mean-pool partial: wave pair-sum over its 2 i-rows, block reduce,
        // plain store of this block's partial (no atomics, no d_out pre-zero needed)
        float s0p = t0 + __shfl_xor(t0, 32, 64);
        float s1p = t1 + __shfl_xor(t1, 32, 64);
        float* poolbuf = (float*)xr_s;            // 8*64 f32 = 2 KB, xr_s is dead
        if (lane < 32) {
            poolbuf[w * 64 + dd * 2]     = s0p;
            poolbuf[w * 64 + dd * 2 + 1] = s1p;
        }
        __syncthreads();
        if (tid < 64) {
            float s = 0.f;
#pragma unroll
            for (int ww = 0; ww < 8; ++ww) s += poolbuf[ww * 64 + tid];
            Hout[((size_t)inst * 32 + ib) * 64 + tid] = s;   // pool partial slab
        }
    }
}

// ---------------- final: reduce 32 pool partials per instance -> d_out ----------------
__global__ __launch_bounds__(64) void kfinal(const float* __restrict__ pool,
                                             float* __restrict__ out)
{
    const int inst = blockIdx.x;     // 0..15
    const int d    = threadIdx.x;    // 0..63
    const float* p = pool + (size_t)inst * 32 * 64 + d;
    float s = 0.f;
#pragma unroll
    for (int ib = 0; ib < 32; ++ib) s += p[ib * 64];
    out[inst * 64 + d] = s * (1.f / NN);
}

extern "C" void kernel_launch(void* const* d_in, const int* in_sizes, int n_in,
                              void* d_out, int out_size, void* d_ws, size_t ws_size,
                              hipStream_t stream)
{
    (void)in_sizes; (void)n_in; (void)out_size; (void)ws_size;
    const float* feat  = (const float*)d_in[0];
    const float* p1_Wl = (const float*)d_in[1],  *p1_Wr = (const float*)d_in[2];
    const float* p1_a  = (const float*)d_in[3],  *p1_b  = (const float*)d_in[4];
    const float* p2_Wl = (const float*)d_in[5],  *p2_Wr = (const float*)d_in[6];
    const float* p2_a  = (const float*)d_in[7],  *p2_b  = (const float*)d_in[8];
    const float* v1_Wl = (const float*)d_in[9],  *v1_Wr = (const float*)d_in[10];
    const float* v1_a  = (const float*)d_in[11], *v1_b  = (const float*)d_in[12];
    const float* v2_Wl = (const float*)d_in[13], *v2_Wr = (const float*)d_in[14];
    const float* v2_a  = (const float*)d_in[15], *v2_b  = (const float*)d_in[16];

    float* ws = (float*)d_ws;
    float* H1 = ws + OFF_H1;
    float* pool = ws + OFF_POOL;
    float* out = (float*)d_out;

    // layer 1 (input: features, K=128)
    kpre<128><<<dim3(32, 16), 256, 0, stream>>>(feat, 0, p1_Wl, p1_Wr, p1_a,
                                                v1_Wl, v1_Wr, v1_a, ws);
    kattn<1><<<dim3(32, 16), 512, 0, stream>>>(ws, p1_b, v1_b, H1);
    // layer 2 (input: H1, K=64) + fused mean-pool partials
    kpre<64><<<dim3(32, 16), 256, 0, stream>>>(H1, 1, p2_Wl, p2_Wr, p2_a,
                                               v2_Wl, v2_Wr, v2_a, ws);
    kattn<2><<<dim3(32, 16), 512, 0, stream>>>(ws, p2_b, v2_b, pool);
    // final pool reduction (overwrites all of d_out deterministically)
    kfinal<<<16, 64, 0, stream>>>(pool, out);
}